// Round 4
// baseline (359.051 us; speedup 1.0000x reference)
//
#include <hip/hip_runtime.h>

#define EPS_F 1e-8f

typedef float  f32x4  __attribute__((ext_vector_type(4)));
typedef __bf16 bf16x8 __attribute__((ext_vector_type(8)));
typedef unsigned short u16x4 __attribute__((ext_vector_type(4)));
typedef unsigned short u16x8 __attribute__((ext_vector_type(8)));

// round-to-nearest-even f32 -> bf16 bits (inputs finite; no NaN handling)
__device__ inline unsigned short f2bf(float x) {
  unsigned int u = __float_as_uint(x);
  u += 0x7fffu + ((u >> 16) & 1u);
  return (unsigned short)(u >> 16);
}

// Pre-kernel: normalize each prototype row to unit length, store bf16 bits.
__global__ __launch_bounds__(256) void proto_norm_kernel(
    const float* __restrict__ proto, unsigned short* __restrict__ Bn)
{
  const int tid = threadIdx.x;
  const int g   = tid & 31;
  const int row = blockIdx.x * 8 + (tid >> 5);
  const float4 v = *(const float4*)&proto[row * 128 + g * 4];
  float ss = v.x*v.x + v.y*v.y + v.z*v.z + v.w*v.w;
  #pragma unroll
  for (int m = 16; m >= 1; m >>= 1) ss += __shfl_xor(ss, m);
  const float rn = 1.0f / fmaxf(sqrtf(ss), EPS_F);
  u16x4 b;
  b[0] = f2bf(v.x * rn); b[1] = f2bf(v.y * rn);
  b[2] = f2bf(v.z * rn); b[3] = f2bf(v.w * rn);
  *(u16x4*)&Bn[row * 128 + g * 4] = b;
}

// Main kernel: LDS-free, barrier-free, 4 blocks/CU resident (grid = 1024 =
// exactly 4/CU -> single balanced round, no tail). Wave = 32 rows x 512 cols.
// A in registers (bf16, fused norm); B streamed from L2 in 16-col steps,
// 2-deep register double buffer. MFMA operands swapped so each thread holds
// 4 consecutive output cols -> coalesced dwordx4 nontemporal stores.
__global__ __launch_bounds__(256, 4) void hproto_kernel(
    const float* __restrict__ emb, const unsigned short* __restrict__ Bn,
    float* __restrict__ out)
{
  constexpr int CD = 128;
  constexpr int KP = 512;

  const int tid  = threadIdx.x;
  const int lane = tid & 63;
  const int wave = tid >> 6;
  const int lo   = lane & 15;
  const int hi   = lane >> 4;
  const long rbase = (long)blockIdx.x * 128 + wave * 32;

  bf16x8 af[2][4];   // A frags: row = rbase + m*16 + lo, k = kk*32 + hi*8
  float  re[2];
  bf16x8 bufA[4], bufB[4];   // 16-col B step double buffer

  auto loadB = [&](bf16x8 (&dst)[4], int s) {
    const unsigned short* bp = Bn + (s * 16 + lo) * CD + hi * 8;
    #pragma unroll
    for (int kk = 0; kk < 4; ++kk)
      dst[kk] = *(const bf16x8*)(bp + kk * 32);
  };

  // ---- prologue: issue A (HBM, long pole) first, then B steps 0/1 ----
  f32x4 a0[4][2], a1[4][2];
  {
    const float* rp0 = emb + (rbase + lo) * CD + hi * 8;
    const float* rp1 = emb + (rbase + 16 + lo) * CD + hi * 8;
    #pragma unroll
    for (int kk = 0; kk < 4; ++kk) {
      a0[kk][0] = *(const f32x4*)(rp0 + kk * 32);
      a0[kk][1] = *(const f32x4*)(rp0 + kk * 32 + 4);
    }
    loadB(bufA, 0);
    loadB(bufB, 1);
    #pragma unroll
    for (int kk = 0; kk < 4; ++kk) {
      a1[kk][0] = *(const f32x4*)(rp1 + kk * 32);
      a1[kk][1] = *(const f32x4*)(rp1 + kk * 32 + 4);
    }
  }

  // ---- convert A to bf16 in-register, fused row norms ----
  auto convert = [&](f32x4 (&a)[4][2], int m) {
    float ss = 0.f;
    #pragma unroll
    for (int kk = 0; kk < 4; ++kk) {
      u16x8 b;
      #pragma unroll
      for (int j = 0; j < 4; ++j) {
        ss += a[kk][0][j] * a[kk][0][j] + a[kk][1][j] * a[kk][1][j];
        b[j]     = f2bf(a[kk][0][j]);
        b[4 + j] = f2bf(a[kk][1][j]);
      }
      af[m][kk] = __builtin_bit_cast(bf16x8, b);
    }
    // 4 lanes (hi=0..3) with same lo jointly hold the full 128-elem row
    ss += __shfl_xor(ss, 16);
    ss += __shfl_xor(ss, 32);
    re[m] = 1.0f / fmaxf(sqrtf(ss), EPS_F);
  };
  convert(a0, 0);
  convert(a1, 1);

  float* const ob = out + (rbase + lo) * KP + hi * 4;

  auto compute = [&](bf16x8 (&buf)[4], int s) {
    f32x4 acc[2] = {f32x4{0.f,0.f,0.f,0.f}, f32x4{0.f,0.f,0.f,0.f}};
    #pragma unroll
    for (int kk = 0; kk < 4; ++kk) {
      acc[0] = __builtin_amdgcn_mfma_f32_16x16x32_bf16(buf[kk], af[0][kk], acc[0], 0, 0, 0);
      acc[1] = __builtin_amdgcn_mfma_f32_16x16x32_bf16(buf[kk], af[1][kk], acc[1], 0, 0, 0);
    }
    // thread holds out[row = rbase+m*16+lo][col = s*16 + hi*4 + j]
    #pragma unroll
    for (int m = 0; m < 2; ++m) {
      f32x4 v;
      #pragma unroll
      for (int j = 0; j < 4; ++j) {
        float d = fmaf(-acc[m][j], re[m], 1.0f);   // d = 1 - cos
        v[j] = -(d * d);
      }
      __builtin_nontemporal_store(v, (f32x4*)(ob + m * 16 * KP + s * 16));
    }
  };

  // ---- 32 steps of 16 cols, 2-deep register pipeline ----
  #pragma unroll 1
  for (int t = 0; t < 16; ++t) {
    compute(bufA, 2 * t);
    if (t < 15) loadB(bufA, 2 * t + 2);
    compute(bufB, 2 * t + 1);
    if (t < 15) loadB(bufB, 2 * t + 3);
  }
}

extern "C" void kernel_launch(void* const* d_in, const int* in_sizes, int n_in,
                              void* d_out, int out_size, void* d_ws, size_t ws_size,
                              hipStream_t stream) {
  const float* emb   = (const float*)d_in[0];
  const float* proto = (const float*)d_in[1];
  float* out = (float*)d_out;
  unsigned short* Bn = (unsigned short*)d_ws;   // 512*128*2 = 128 KB scratch
  const int C = 128;
  const int N = in_sizes[0] / C;   // 131072
  const int K = in_sizes[1] / C;   // 512
  proto_norm_kernel<<<K / 8, 256, 0, stream>>>(proto, Bn);
  hproto_kernel<<<N / 128, 256, 0, stream>>>(emb, Bn, out);
}